// Round 1
// baseline (180.797 us; speedup 1.0000x reference)
//
#include <hip/hip_runtime.h>

// Overlap-add renderer, scatter->gather inversion.
// out[b, s] = sum_{i: t_i <= s} x[b, i, s - t_i],  t_i = indices[b,i] * 256
//
// B=64, E=16, S=32768, STEP=256, N_FRAMES=128. Output (B,1,S) fp32.
// Since t_i >= 0 and s < S, the "s - t_i < S" bound is automatic.

#define B_SZ 64
#define E_SZ 16
#define S_SZ 32768
#define STEP_SZ 256

// One block = one batch row x 1024 contiguous samples (256 threads x float4).
// blockIdx.x = b * 32 + chunk   (32 chunks of 1024 samples per batch row)
__global__ __launch_bounds__(256) void render_kernel(
    const float* __restrict__ x,      // (B, E, S)
    const int* __restrict__ indices,  // (B, E) int32
    float* __restrict__ out)          // (B, S)
{
    const int b     = blockIdx.x >> 5;          // wave-uniform -> scalar loads of indices
    const int chunk = blockIdx.x & 31;
    const int s4    = (chunk << 10) + (threadIdx.x << 2);  // first of 4 samples

    float4 acc = make_float4(0.f, 0.f, 0.f, 0.f);

    const float* xb = x + (size_t)b * E_SZ * S_SZ;

    #pragma unroll
    for (int i = 0; i < E_SZ; ++i) {
        const int t = indices[b * E_SZ + i] * STEP_SZ;  // multiple of 256
        if (s4 >= t) {
            // t multiple of 256, s4 multiple of 4 -> aligned float4, all 4 valid
            const float4 v = *(const float4*)(xb + (size_t)i * S_SZ + (s4 - t));
            acc.x += v.x; acc.y += v.y; acc.z += v.z; acc.w += v.w;
        }
    }

    *(float4*)(out + (size_t)b * S_SZ + s4) = acc;
}

extern "C" void kernel_launch(void* const* d_in, const int* in_sizes, int n_in,
                              void* d_out, int out_size, void* d_ws, size_t ws_size,
                              hipStream_t stream) {
    const float* x       = (const float*)d_in[0];
    const int*   indices = (const int*)d_in[1];
    float*       out     = (float*)d_out;

    const int n_blocks = B_SZ * (S_SZ / (256 * 4));  // 64 * 32 = 2048
    render_kernel<<<n_blocks, 256, 0, stream>>>(x, indices, out);
}

// Round 3
// 172.762 us; speedup vs baseline: 1.0465x; 1.0465x over previous
//
#include <hip/hip_runtime.h>

// Overlap-add renderer, scatter->gather inversion.
// out[b, s] = sum_{i: t_i <= s} x[b, i, s - t_i],  t_i = indices[b,i] * 256
//
// B=64, E=16, S=32768, STEP=256. Output (B,1,S) fp32.
// t_i >= 0 and s < S, so the upper bound s - t_i < S is automatic.
//
// R1 post-mortem: dur_us=180.8 dominated by harness ops (512 MiB ws re-poison
// fills at ~83 us each); this kernel is <82 us, roofline arithmetic ~14 us
// (72 MiB moved / 6.4 TB/s + launch overhead).
// R2 failed: __builtin_nontemporal_* rejects HIP_vector_type pointers.
// R3: use clang ext_vector_type(4) float (same layout/alignment) so the
// nontemporal builtins compile — x streamed once, out write-once.

#define B_SZ 64
#define E_SZ 16
#define S_SZ 32768
#define STEP_SZ 256

typedef float v4f __attribute__((ext_vector_type(4)));

// One block = one batch row x 1024 contiguous samples (256 threads x v4f).
// blockIdx.x = b * 32 + chunk. b is wave-uniform -> index loads scalarize.
// Within a wave, s4 spans one aligned 256-sample window and t is a multiple
// of 256, so the predicate (s4 >= t) is wave-uniform: no divergence.
__global__ __launch_bounds__(256) void render_kernel(
    const float* __restrict__ x,      // (B, E, S)
    const int* __restrict__ indices,  // (B, E) int32
    float* __restrict__ out)          // (B, S)
{
    const int b     = blockIdx.x >> 5;
    const int chunk = blockIdx.x & 31;
    const int s4    = (chunk << 10) + (threadIdx.x << 2);  // first of 4 samples

    v4f acc = (v4f)(0.f);

    const float* xb = x + (size_t)b * E_SZ * S_SZ;

    #pragma unroll
    for (int i = 0; i < E_SZ; ++i) {
        const int t = indices[b * E_SZ + i] * STEP_SZ;  // multiple of 256
        if (s4 >= t) {
            // t multiple of 256, s4 multiple of 4 -> aligned 16B, all 4 valid.
            // Streamed exactly once: nontemporal load.
            const v4f v = __builtin_nontemporal_load(
                (const v4f*)(xb + (size_t)i * S_SZ + (s4 - t)));
            acc += v;
        }
    }

    // Write-once output, never re-read by us: nontemporal store.
    __builtin_nontemporal_store(acc, (v4f*)(out + (size_t)b * S_SZ + s4));
}

extern "C" void kernel_launch(void* const* d_in, const int* in_sizes, int n_in,
                              void* d_out, int out_size, void* d_ws, size_t ws_size,
                              hipStream_t stream) {
    const float* x       = (const float*)d_in[0];
    const int*   indices = (const int*)d_in[1];
    float*       out     = (float*)d_out;

    const int n_blocks = B_SZ * (S_SZ / (256 * 4));  // 64 * 32 = 2048
    render_kernel<<<n_blocks, 256, 0, stream>>>(x, indices, out);
}